// Round 8
// baseline (43.996 us; speedup 1.0000x reference)
//
#include <hip/hip_runtime.h>
#include <stdint.h>

#define IMG  512
#define CPT  8
#define CGRP (IMG / CPT)    // 64 col-groups per row

typedef float    v2f   __attribute__((ext_vector_type(2)));
typedef _Float16 h2    __attribute__((ext_vector_type(2)));
typedef __fp16   f16x2 __attribute__((ext_vector_type(2)));

static __device__ __forceinline__ h2 pkrtz(float a, float b) {
    f16x2 t = __builtin_amdgcn_cvt_pkrtz(a, b);   // v_cvt_pkrtz_f16_f32
    return __builtin_bit_cast(h2, t);
}

#if __has_builtin(__builtin_amdgcn_fdot2)
#define FDOT2(a, b, c) __builtin_amdgcn_fdot2((a), (b), (c), false)
#else
static __device__ __forceinline__ float fdot2_sw(h2 a, h2 b, float c) {
    return fmaf((float)a.x, (float)b.x, fmaf((float)a.y, (float)b.y, c));
}
#define FDOT2(a, b, c) fdot2_sw((a), (b), (c))
#endif

// tanh via Pade[7/6] (truncated continued fraction):
//   tanh(x) ~= x*(u^2 + 105u + 945) / (15u^2 + 420u + 945), u = x^2
// |err| <= 1.25e-3 on |x| <= 3.77; for |x| > 3.77 the ratio stays >= 1 and
// grows, so clamping to [-1,1] bounds err by 1-tanh(3.77) ~= 1.2e-3.
// Packed evaluation, ONE v_rcp_f32 for BOTH pixels of the pair:
//   r = rcp(dx*dy); 1/dx = r*dy; 1/dy = r*dx   (d >= 945 > 0 always)
static __device__ __forceinline__ v2f tanh2_pade(v2f v) {
    v2f u = v * v;
    v2f t = u + (v2f){105.0f, 105.0f};
    v2f n = __builtin_elementwise_fma(u, t, (v2f){945.0f, 945.0f});
    v2f s = __builtin_elementwise_fma(u, (v2f){15.0f, 15.0f},
                                      (v2f){420.0f, 420.0f});
    v2f d = __builtin_elementwise_fma(u, s, (v2f){945.0f, 945.0f});
    float r = __builtin_amdgcn_rcpf(d.x * d.y);
    v2f rv = { r * d.y, r * d.x };
    v2f q  = (v * n) * rv;
    q = __builtin_elementwise_min(q, (v2f){ 1.0f,  1.0f});
    q = __builtin_elementwise_max(q, (v2f){-1.0f, -1.0f});
    return q;
}

// ws layout (dwords): [0..35] u32 half2 weight pairs u[c][k] (raw, unscaled);
//                     [36..44] w8[c] f32; [45..53] bv[c] f32
__global__ void prepack_kernel(const float* __restrict__ W,
                               const float* __restrict__ B,
                               uint32_t* __restrict__ ws) {
    int c = threadIdx.x;
    if (c < 9) {
        const float* wc = W + c * 9;
#pragma unroll
        for (int k = 0; k < 4; ++k) {
            h2 t = pkrtz(wc[2 * k], wc[2 * k + 1]);
            ws[c * 4 + k] = __builtin_bit_cast(uint32_t, t);
        }
        ((float*)ws)[36 + c] = wc[8];
        ((float*)ws)[45 + c] = B[c];
    }
}

__global__ __launch_bounds__(256) void fused_convtap_kernel(
    const float* __restrict__ x,       // (B,1,512,512)
    const uint32_t* __restrict__ wsu,  // prepacked weights
    float* __restrict__ out)           // (B,1,512,512)
{
    const float* w8v = (const float*)(wsu + 36);
    const float* bvv = (const float*)(wsu + 45);

    const int tid = blockIdx.x * 256 + threadIdx.x;
    const int xg  = tid & (CGRP - 1);
    const int row = tid >> 6;            // b*IMG + y
    const int y   = row & (IMG - 1);
    const int x0  = xg * CPT;

    const float* xr = x + (size_t)row * IMG;

    // Uniform prepacked weights -> SGPRs.
    h2 u[9][4];
#pragma unroll
    for (int c = 0; c < 9; ++c)
#pragma unroll
        for (int k = 0; k < 4; ++k)
            u[c][k] = __builtin_bit_cast(h2, wsu[c * 4 + k]);
    float w8[9], bv[9];
#pragma unroll
    for (int c = 0; c < 9; ++c) { w8[c] = w8v[c]; bv[c] = bvv[c]; }

    const bool has_l = (x0 > 0);
    const bool has_r = (x0 < IMG - CPT);

    // Input rows y-1, y, y+1; columns x0-1 .. x0+8 (zero-padded outside).
    float r0[10], r1[10], r2[10];
    auto load_row = [&](const float* p, float* r) {
        float4 a = *reinterpret_cast<const float4*>(p + x0);
        float4 c = *reinterpret_cast<const float4*>(p + x0 + 4);
        r[1] = a.x; r[2] = a.y; r[3] = a.z; r[4] = a.w;
        r[5] = c.x; r[6] = c.y; r[7] = c.z; r[8] = c.w;
        r[0] = has_l ? p[x0 - 1] : 0.0f;
        r[9] = has_r ? p[x0 + 8] : 0.0f;
    };
    auto zero_row = [&](float* r) {
#pragma unroll
        for (int k = 0; k < 10; ++k) r[k] = 0.0f;
    };

    if (y > 0)       load_row(xr - IMG, r0); else zero_row(r0);
                     load_row(xr,       r1);
    if (y < IMG - 1) load_row(xr + IMG, r2); else zero_row(r2);

    float o[CPT];
#pragma unroll
    for (int tp = 0; tp < 4; ++tp) {
        const int t0 = 2 * tp;
        // f16 K-pairs for pixels t0 and t0+1:
        // A=(p0q0,p0q1) B=(p0q2,p1q0) C=(p1q1,p1q2) D=(p2q0,p2q1), lone p2q2 f32
        h2 A0 = pkrtz(r0[t0],     r0[t0 + 1]);
        h2 B0 = pkrtz(r0[t0 + 2], r1[t0]);
        h2 C0 = pkrtz(r1[t0 + 1], r1[t0 + 2]);
        h2 D0 = pkrtz(r2[t0],     r2[t0 + 1]);
        h2 A1 = pkrtz(r0[t0 + 1], r0[t0 + 2]);
        h2 B1 = pkrtz(r0[t0 + 3], r1[t0 + 1]);
        h2 C1 = pkrtz(r1[t0 + 2], r1[t0 + 3]);
        h2 D1 = pkrtz(r2[t0 + 1], r2[t0 + 2]);

        v2f acc = {0.0f, 0.0f};
#pragma unroll
        for (int c = 0; c < 9; ++c) {
            float fx = bv[c], fy = bv[c];
            fx = FDOT2(A0, u[c][0], fx);
            fx = FDOT2(B0, u[c][1], fx);
            fx = FDOT2(C0, u[c][2], fx);
            fx = FDOT2(D0, u[c][3], fx);
            fx = fmaf(r2[t0 + 2], w8[c], fx);
            fy = FDOT2(A1, u[c][0], fy);
            fy = FDOT2(B1, u[c][1], fy);
            fy = FDOT2(C1, u[c][2], fy);
            fy = FDOT2(D1, u[c][3], fy);
            fy = fmaf(r2[t0 + 3], w8[c], fy);

            v2f th = tanh2_pade((v2f){fx, fy});

            // tap stage: out += patch[j][i] * tanh(fc_c), c = 3i+j (f32 path)
            const int i = c / 3, j = c - 3 * i;
            const float* rj = (j == 0) ? r0 : (j == 1) ? r1 : r2;
            v2f px2 = { rj[t0 + i], rj[t0 + 1 + i] };
            acc = __builtin_elementwise_fma(px2, th, acc);
        }
        o[t0] = acc.x; o[t0 + 1] = acc.y;
    }

    float* orow = out + (size_t)row * IMG + x0;
    *reinterpret_cast<float4*>(orow)     = make_float4(o[0], o[1], o[2], o[3]);
    *reinterpret_cast<float4*>(orow + 4) = make_float4(o[4], o[5], o[6], o[7]);
}

extern "C" void kernel_launch(void* const* d_in, const int* in_sizes, int n_in,
                              void* d_out, int out_size, void* d_ws, size_t ws_size,
                              hipStream_t stream) {
    const float* x  = (const float*)d_in[0];   // (B,1,512,512) f32
    const float* W  = (const float*)d_in[1];   // (9,1,3,3)     f32
    const float* Bv = (const float*)d_in[2];   // (9,)          f32
    float* out = (float*)d_out;
    uint32_t* ws = (uint32_t*)d_ws;

    prepack_kernel<<<1, 64, 0, stream>>>(W, Bv, ws);

    const int batch   = in_sizes[0] / (IMG * IMG);   // 32
    const int threads = batch * IMG * CGRP;          // 1,048,576
    const int grid    = threads / 256;               // 4096
    fused_convtap_kernel<<<grid, 256, 0, stream>>>(x, ws, out);
}

// Round 9
// 42.361 us; speedup vs baseline: 1.0386x; 1.0386x over previous
//
#include <hip/hip_runtime.h>
#include <stdint.h>

#define IMG  512
#define CPT  8
#define CGRP (IMG / CPT)    // 64 col-groups per row

typedef float    v2f   __attribute__((ext_vector_type(2)));
typedef _Float16 h2    __attribute__((ext_vector_type(2)));
typedef __fp16   f16x2 __attribute__((ext_vector_type(2)));

static __device__ __forceinline__ h2 pkrtz(float a, float b) {
    f16x2 t = __builtin_amdgcn_cvt_pkrtz(a, b);   // v_cvt_pkrtz_f16_f32
    return __builtin_bit_cast(h2, t);
}

#if __has_builtin(__builtin_amdgcn_fdot2)
#define FDOT2(a, b, c) __builtin_amdgcn_fdot2((a), (b), (c), false)
#else
static __device__ __forceinline__ float fdot2_sw(h2 a, h2 b, float c) {
    return fmaf((float)a.x, (float)b.x, fmaf((float)a.y, (float)b.y, c));
}
#define FDOT2(a, b, c) fdot2_sw((a), (b), (c))
#endif

// Forced dual-rate packed f32 ops (compiler won't emit these from float2
// elementwise ops -- R2/R8 evidence). "v" on an 8-byte vector type gives an
// even-aligned VGPR pair.
static __device__ __forceinline__ v2f pk_mul(v2f a, v2f b) {
    v2f d;
    asm("v_pk_mul_f32 %0, %1, %2" : "=v"(d) : "v"(a), "v"(b));
    return d;
}
static __device__ __forceinline__ v2f pk_add(v2f a, v2f b) {
    v2f d;
    asm("v_pk_add_f32 %0, %1, %2" : "=v"(d) : "v"(a), "v"(b));
    return d;
}
static __device__ __forceinline__ v2f pk_fma(v2f a, v2f b, v2f c) {
    v2f d;
    asm("v_pk_fma_f32 %0, %1, %2, %3" : "=v"(d) : "v"(a), "v"(b), "v"(c));
    return d;
}

// tanh via Pade[7/6]: tanh(x) ~= x*(u^2+105u+945)/(15u^2+420u+945), u=x^2.
// |err|<=1.25e-3 on |x|<=3.77; beyond that ratio >= 1 so med3-clamp to
// [-1,1] bounds err. One v_rcp_f32 for BOTH pixels (d >= 945 > 0 always).
static __device__ __forceinline__ v2f tanh2_pade_pk(v2f v, v2f c105, v2f c945,
                                                    v2f c15, v2f c420) {
    v2f u = pk_mul(v, v);
    v2f n = pk_fma(u, pk_add(u, c105), c945);
    v2f d = pk_fma(u, pk_fma(u, c15, c420), c945);
    float r = __builtin_amdgcn_rcpf(d.x * d.y);
    v2f rv = { r * d.y, r * d.x };
    v2f q  = pk_mul(pk_mul(v, n), rv);
    return (v2f){ __builtin_amdgcn_fmed3f(q.x, -1.0f, 1.0f),
                  __builtin_amdgcn_fmed3f(q.y, -1.0f, 1.0f) };
}

// ws layout (dwords): [0..35] u32 half2 weight pairs u[c][k] (raw, unscaled);
//                     [36..44] w8[c] f32; [45..53] bv[c] f32
__global__ void prepack_kernel(const float* __restrict__ W,
                               const float* __restrict__ B,
                               uint32_t* __restrict__ ws) {
    int c = threadIdx.x;
    if (c < 9) {
        const float* wc = W + c * 9;
#pragma unroll
        for (int k = 0; k < 4; ++k) {
            h2 t = pkrtz(wc[2 * k], wc[2 * k + 1]);
            ws[c * 4 + k] = __builtin_bit_cast(uint32_t, t);
        }
        ((float*)ws)[36 + c] = wc[8];
        ((float*)ws)[45 + c] = B[c];
    }
}

__global__ __launch_bounds__(256) void fused_convtap_kernel(
    const float* __restrict__ x,       // (B,1,512,512)
    const uint32_t* __restrict__ wsu,  // prepacked weights
    float* __restrict__ out)           // (B,1,512,512)
{
    const float* w8v = (const float*)(wsu + 36);
    const float* bvv = (const float*)(wsu + 45);

    const int tid = blockIdx.x * 256 + threadIdx.x;
    const int xg  = tid & (CGRP - 1);
    const int row = tid >> 6;            // b*IMG + y
    const int y   = row & (IMG - 1);
    const int x0  = xg * CPT;

    const float* xr = x + (size_t)row * IMG;

    // Uniform prepacked weights -> SGPRs.
    h2 u[9][4];
#pragma unroll
    for (int c = 0; c < 9; ++c)
#pragma unroll
        for (int k = 0; k < 4; ++k)
            u[c][k] = __builtin_bit_cast(h2, wsu[c * 4 + k]);
    float w8[9], bv[9];
#pragma unroll
    for (int c = 0; c < 9; ++c) { w8[c] = w8v[c]; bv[c] = bvv[c]; }

    // Pade constants, materialized once into VGPR pairs for the asm ops.
    const v2f c105 = {105.0f, 105.0f};
    const v2f c945 = {945.0f, 945.0f};
    const v2f c15  = { 15.0f,  15.0f};
    const v2f c420 = {420.0f, 420.0f};

    const bool has_l = (x0 > 0);
    const bool has_r = (x0 < IMG - CPT);

    // Input rows y-1, y, y+1; columns x0-1 .. x0+8 (zero-padded outside).
    float r0[10], r1[10], r2[10];
    auto load_row = [&](const float* p, float* r) {
        float4 a = *reinterpret_cast<const float4*>(p + x0);
        float4 c = *reinterpret_cast<const float4*>(p + x0 + 4);
        r[1] = a.x; r[2] = a.y; r[3] = a.z; r[4] = a.w;
        r[5] = c.x; r[6] = c.y; r[7] = c.z; r[8] = c.w;
        r[0] = has_l ? p[x0 - 1] : 0.0f;
        r[9] = has_r ? p[x0 + 8] : 0.0f;
    };
    auto zero_row = [&](float* r) {
#pragma unroll
        for (int k = 0; k < 10; ++k) r[k] = 0.0f;
    };

    if (y > 0)       load_row(xr - IMG, r0); else zero_row(r0);
                     load_row(xr,       r1);
    if (y < IMG - 1) load_row(xr + IMG, r2); else zero_row(r2);

    float o[CPT];
#pragma unroll
    for (int tp = 0; tp < 4; ++tp) {
        const int t0 = 2 * tp;
        // f16 K-pairs for pixels t0 and t0+1:
        // A=(p0q0,p0q1) B=(p0q2,p1q0) C=(p1q1,p1q2) D=(p2q0,p2q1), lone p2q2 f32
        h2 A0 = pkrtz(r0[t0],     r0[t0 + 1]);
        h2 B0 = pkrtz(r0[t0 + 2], r1[t0]);
        h2 C0 = pkrtz(r1[t0 + 1], r1[t0 + 2]);
        h2 D0 = pkrtz(r2[t0],     r2[t0 + 1]);
        h2 A1 = pkrtz(r0[t0 + 1], r0[t0 + 2]);
        h2 B1 = pkrtz(r0[t0 + 3], r1[t0 + 1]);
        h2 C1 = pkrtz(r1[t0 + 2], r1[t0 + 3]);
        h2 D1 = pkrtz(r2[t0 + 1], r2[t0 + 2]);

        v2f acc = {0.0f, 0.0f};
#pragma unroll
        for (int c = 0; c < 9; ++c) {
            float fx = bv[c], fy = bv[c];
            fx = FDOT2(A0, u[c][0], fx);
            fx = FDOT2(B0, u[c][1], fx);
            fx = FDOT2(C0, u[c][2], fx);
            fx = FDOT2(D0, u[c][3], fx);
            fx = fmaf(r2[t0 + 2], w8[c], fx);
            fy = FDOT2(A1, u[c][0], fy);
            fy = FDOT2(B1, u[c][1], fy);
            fy = FDOT2(C1, u[c][2], fy);
            fy = FDOT2(D1, u[c][3], fy);
            fy = fmaf(r2[t0 + 3], w8[c], fy);

            v2f th = tanh2_pade_pk((v2f){fx, fy}, c105, c945, c15, c420);

            // tap stage: out += patch[j][i] * tanh(fc_c), c = 3i+j
            const int i = c / 3, j = c - 3 * i;
            const float* rj = (j == 0) ? r0 : (j == 1) ? r1 : r2;
            v2f px2 = { rj[t0 + i], rj[t0 + 1 + i] };
            acc = pk_fma(px2, th, acc);
        }
        o[t0] = acc.x; o[t0 + 1] = acc.y;
    }

    float* orow = out + (size_t)row * IMG + x0;
    *reinterpret_cast<float4*>(orow)     = make_float4(o[0], o[1], o[2], o[3]);
    *reinterpret_cast<float4*>(orow + 4) = make_float4(o[4], o[5], o[6], o[7]);
}

extern "C" void kernel_launch(void* const* d_in, const int* in_sizes, int n_in,
                              void* d_out, int out_size, void* d_ws, size_t ws_size,
                              hipStream_t stream) {
    const float* x  = (const float*)d_in[0];   // (B,1,512,512) f32
    const float* W  = (const float*)d_in[1];   // (9,1,3,3)     f32
    const float* Bv = (const float*)d_in[2];   // (9,)          f32
    float* out = (float*)d_out;
    uint32_t* ws = (uint32_t*)d_ws;

    prepack_kernel<<<1, 64, 0, stream>>>(W, Bv, ws);

    const int batch   = in_sizes[0] / (IMG * IMG);   // 32
    const int threads = batch * IMG * CGRP;          // 1,048,576
    const int grid    = threads / 256;               // 4096
    fused_convtap_kernel<<<grid, 256, 0, stream>>>(x, ws, out);
}

// Round 10
// 39.774 us; speedup vs baseline: 1.1061x; 1.0650x over previous
//
#include <hip/hip_runtime.h>
#include <stdint.h>

#define IMG  512
#define CPT  8
#define CGRP (IMG / CPT)    // 64 col-groups per row

typedef float    v2f   __attribute__((ext_vector_type(2)));
typedef _Float16 h2    __attribute__((ext_vector_type(2)));
typedef __fp16   f16x2 __attribute__((ext_vector_type(2)));

static __device__ __forceinline__ h2 pkrtz(float a, float b) {
    f16x2 t = __builtin_amdgcn_cvt_pkrtz(a, b);   // v_cvt_pkrtz_f16_f32
    return __builtin_bit_cast(h2, t);
}

#if __has_builtin(__builtin_amdgcn_fdot2)
#define FDOT2(a, b, c) __builtin_amdgcn_fdot2((a), (b), (c), false)
#else
static __device__ __forceinline__ float fdot2_sw(h2 a, h2 b, float c) {
    return fmaf((float)a.x, (float)b.x, fmaf((float)a.y, (float)b.y, c));
}
#define FDOT2(a, b, c) fdot2_sw((a), (b), (c))
#endif

// Forced dual-rate packed f32 ops (compiler won't emit from float2 elementwise).
static __device__ __forceinline__ v2f pk_mul(v2f a, v2f b) {
    v2f d;
    asm("v_pk_mul_f32 %0, %1, %2" : "=v"(d) : "v"(a), "v"(b));
    return d;
}
static __device__ __forceinline__ v2f pk_add(v2f a, v2f b) {
    v2f d;
    asm("v_pk_add_f32 %0, %1, %2" : "=v"(d) : "v"(a), "v"(b));
    return d;
}
static __device__ __forceinline__ v2f pk_fma(v2f a, v2f b, v2f c) {
    v2f d;
    asm("v_pk_fma_f32 %0, %1, %2, %3" : "=v"(d) : "v"(a), "v"(b), "v"(c));
    return d;
}

// tanh via Pade[7/6]: tanh(x) ~= x*(u^2+105u+945)/(15u^2+420u+945), u=x^2.
// |err|<=1.25e-3 on |x|<=3.77; beyond that ratio >= 1 so med3-clamp to
// [-1,1] bounds err. One v_rcp_f32 for BOTH pixels (d >= 945 > 0 always).
static __device__ __forceinline__ v2f tanh2_pade_pk(v2f v, v2f c105, v2f c945,
                                                    v2f c15, v2f c420) {
    v2f u = pk_mul(v, v);
    v2f n = pk_fma(u, pk_add(u, c105), c945);
    v2f d = pk_fma(u, pk_fma(u, c15, c420), c945);
    float r = __builtin_amdgcn_rcpf(d.x * d.y);
    v2f rv = { r * d.y, r * d.x };
    v2f q  = pk_mul(pk_mul(v, n), rv);
    return (v2f){ __builtin_amdgcn_fmed3f(q.x, -1.0f, 1.0f),
                  __builtin_amdgcn_fmed3f(q.y, -1.0f, 1.0f) };
}

// Single fused kernel: weight prep inlined (uniform s_loads + 36 pkrtz),
// no separate prepack dispatch. __launch_bounds__(256,4): VGPR cap 128 --
// relaxes the register-pressure heuristic so the scheduler can keep multiple
// conv/tanh dependency chains in flight (R9 post-mortem: 40-VGPR codegen was
// dependency-latency starved at ~30-50% per-SIMD issue utilization).
__global__ __launch_bounds__(256, 4) void fused_convtap_kernel(
    const float* __restrict__ x,   // (B,1,512,512)
    const float* __restrict__ W,   // (9,1,3,3)
    const float* __restrict__ Bv,  // (9,)
    float* __restrict__ out)       // (B,1,512,512)
{
    const int tid = blockIdx.x * 256 + threadIdx.x;
    const int xg  = tid & (CGRP - 1);
    const int row = tid >> 6;            // b*IMG + y
    const int y   = row & (IMG - 1);
    const int x0  = xg * CPT;

    const float* xr = x + (size_t)row * IMG;

    // Uniform weights: s_loads; f16 pairs built per-thread (wave-uniform VGPRs).
    // u[c][k] = (wc[2k], wc[2k+1]) f16; w8[c] = wc[8]; bv[c] = bias[c].
    h2 u[9][4];
    float w8[9], bv[9];
#pragma unroll
    for (int c = 0; c < 9; ++c) {
#pragma unroll
        for (int k = 0; k < 4; ++k)
            u[c][k] = pkrtz(W[c * 9 + 2 * k], W[c * 9 + 2 * k + 1]);
        w8[c] = W[c * 9 + 8];
        bv[c] = Bv[c];
    }

    // Pade constants in VGPR pairs for the asm ops.
    const v2f c105 = {105.0f, 105.0f};
    const v2f c945 = {945.0f, 945.0f};
    const v2f c15  = { 15.0f,  15.0f};
    const v2f c420 = {420.0f, 420.0f};

    const bool has_l = (x0 > 0);
    const bool has_r = (x0 < IMG - CPT);

    // Input rows y-1, y, y+1; columns x0-1 .. x0+8 (zero-padded outside).
    float r0[10], r1[10], r2[10];
    auto load_row = [&](const float* p, float* r) {
        float4 a = *reinterpret_cast<const float4*>(p + x0);
        float4 c = *reinterpret_cast<const float4*>(p + x0 + 4);
        r[1] = a.x; r[2] = a.y; r[3] = a.z; r[4] = a.w;
        r[5] = c.x; r[6] = c.y; r[7] = c.z; r[8] = c.w;
        r[0] = has_l ? p[x0 - 1] : 0.0f;
        r[9] = has_r ? p[x0 + 8] : 0.0f;
    };
    auto zero_row = [&](float* r) {
#pragma unroll
        for (int k = 0; k < 10; ++k) r[k] = 0.0f;
    };

    if (y > 0)       load_row(xr - IMG, r0); else zero_row(r0);
                     load_row(xr,       r1);
    if (y < IMG - 1) load_row(xr + IMG, r2); else zero_row(r2);

    float o[CPT];
    // Two pair-groups; within a group, TWO pixel-pairs' chains are textually
    // interleaved so the scheduler keeps >=4 independent dep-chains in flight.
#pragma unroll
    for (int g = 0; g < 2; ++g) {
        const int ta = 4 * g;        // pair a: pixels ta, ta+1
        const int tb = 4 * g + 2;    // pair b: pixels tb, tb+1

        // f16 K-pairs (A=(p0q0,p0q1) B=(p0q2,p1q0) C=(p1q1,p1q2) D=(p2q0,p2q1))
        h2 Aa0 = pkrtz(r0[ta],     r0[ta + 1]);
        h2 Ab0 = pkrtz(r0[tb],     r0[tb + 1]);
        h2 Ba0 = pkrtz(r0[ta + 2], r1[ta]);
        h2 Bb0 = pkrtz(r0[tb + 2], r1[tb]);
        h2 Ca0 = pkrtz(r1[ta + 1], r1[ta + 2]);
        h2 Cb0 = pkrtz(r1[tb + 1], r1[tb + 2]);
        h2 Da0 = pkrtz(r2[ta],     r2[ta + 1]);
        h2 Db0 = pkrtz(r2[tb],     r2[tb + 1]);
        h2 Aa1 = pkrtz(r0[ta + 1], r0[ta + 2]);
        h2 Ab1 = pkrtz(r0[tb + 1], r0[tb + 2]);
        h2 Ba1 = pkrtz(r0[ta + 3], r1[ta + 1]);
        h2 Bb1 = pkrtz(r0[tb + 3], r1[tb + 1]);
        h2 Ca1 = pkrtz(r1[ta + 2], r1[ta + 3]);
        h2 Cb1 = pkrtz(r1[tb + 2], r1[tb + 3]);
        h2 Da1 = pkrtz(r2[ta + 1], r2[ta + 2]);
        h2 Db1 = pkrtz(r2[tb + 1], r2[tb + 2]);

        v2f accA = {0.0f, 0.0f};
        v2f accB = {0.0f, 0.0f};
#pragma unroll
        for (int c = 0; c < 9; ++c) {
            // conv: 4 independent dot2 chains (fxA,fyA,fxB,fyB), interleaved
            float fxA = bv[c], fyA = bv[c], fxB = bv[c], fyB = bv[c];
            fxA = FDOT2(Aa0, u[c][0], fxA);
            fxB = FDOT2(Ab0, u[c][0], fxB);
            fyA = FDOT2(Aa1, u[c][0], fyA);
            fyB = FDOT2(Ab1, u[c][0], fyB);
            fxA = FDOT2(Ba0, u[c][1], fxA);
            fxB = FDOT2(Bb0, u[c][1], fxB);
            fyA = FDOT2(Ba1, u[c][1], fyA);
            fyB = FDOT2(Bb1, u[c][1], fyB);
            fxA = FDOT2(Ca0, u[c][2], fxA);
            fxB = FDOT2(Cb0, u[c][2], fxB);
            fyA = FDOT2(Ca1, u[c][2], fyA);
            fyB = FDOT2(Cb1, u[c][2], fyB);
            fxA = FDOT2(Da0, u[c][3], fxA);
            fxB = FDOT2(Db0, u[c][3], fxB);
            fyA = FDOT2(Da1, u[c][3], fyA);
            fyB = FDOT2(Db1, u[c][3], fyB);
            fxA = fmaf(r2[ta + 2], w8[c], fxA);
            fxB = fmaf(r2[tb + 2], w8[c], fxB);
            fyA = fmaf(r2[ta + 3], w8[c], fyA);
            fyB = fmaf(r2[tb + 3], w8[c], fyB);

            v2f thA = tanh2_pade_pk((v2f){fxA, fyA}, c105, c945, c15, c420);
            v2f thB = tanh2_pade_pk((v2f){fxB, fyB}, c105, c945, c15, c420);

            // tap stage: out += patch[j][i] * tanh(fc_c), c = 3i+j
            const int i = c / 3, j = c - 3 * i;
            const float* rj = (j == 0) ? r0 : (j == 1) ? r1 : r2;
            v2f pxA = { rj[ta + i], rj[ta + 1 + i] };
            v2f pxB = { rj[tb + i], rj[tb + 1 + i] };
            accA = pk_fma(pxA, thA, accA);
            accB = pk_fma(pxB, thB, accB);
        }
        o[ta]     = accA.x; o[ta + 1] = accA.y;
        o[tb]     = accB.x; o[tb + 1] = accB.y;
    }

    float* orow = out + (size_t)row * IMG + x0;
    *reinterpret_cast<float4*>(orow)     = make_float4(o[0], o[1], o[2], o[3]);
    *reinterpret_cast<float4*>(orow + 4) = make_float4(o[4], o[5], o[6], o[7]);
}

extern "C" void kernel_launch(void* const* d_in, const int* in_sizes, int n_in,
                              void* d_out, int out_size, void* d_ws, size_t ws_size,
                              hipStream_t stream) {
    const float* x  = (const float*)d_in[0];   // (B,1,512,512) f32
    const float* W  = (const float*)d_in[1];   // (9,1,3,3)     f32
    const float* Bv = (const float*)d_in[2];   // (9,)          f32
    float* out = (float*)d_out;

    const int batch   = in_sizes[0] / (IMG * IMG);   // 32
    const int threads = batch * IMG * CGRP;          // 1,048,576
    const int grid    = threads / 256;               // 4096
    fused_convtap_kernel<<<grid, 256, 0, stream>>>(x, W, Bv, out);
}